// Round 1
// 253.677 us; speedup vs baseline: 1.3360x; 1.3360x over previous
//
#include <hip/hip_runtime.h>

#define DD 256
#define KK 1024
#define HW 4096
#define NROWSZ 65536
#define OUT_Z 16777216
#define OUT_IDX OUT_Z
#define OUT_LOSS (OUT_Z + NROWSZ)

#define MARGIN 3.0e-4f

// ws layout (bytes)
#define WS_ESQ   0          // float[1024]
#define WS_EH    4096       // _Float16[262144] emb fp16 [k][d]
#define WS_HLIST 528384     // int[65536]
#define WS_HCNT  790528     // int
#define WS_LSUM  790536     // double
#define WS_EMBT  791552     // float[256*1024] = 1 MB, emb^T [d][k]
#define WS_HZ    1840128    // float[hzcap*256] compact exact fp32 z rows (hard rows)

typedef _Float16 f16x8 __attribute__((ext_vector_type(8)));
typedef float f32x4 __attribute__((ext_vector_type(4)));
union U16x8 { uint4 u; f16x8 h; };
typedef unsigned long long u64;

static __device__ __forceinline__ u64 umin64(u64 a, u64 b) { return a < b ? a : b; }
static __device__ __forceinline__ unsigned fkey(float s) {
    unsigned b = __float_as_uint(s);
    unsigned flip = (unsigned)((int)b >> 31) | 0x80000000u;
    return b ^ flip;
}
static __device__ __forceinline__ float funkey(unsigned k) {
    unsigned b = (k & 0x80000000u) ? (k ^ 0x80000000u) : ~k;
    return __uint_as_float(b);
}
static __device__ __forceinline__ unsigned pk16(float a, float b) {
    _Float16 ha = (_Float16)a, hb = (_Float16)b;
    return (unsigned)__builtin_bit_cast(unsigned short, ha)
         | ((unsigned)__builtin_bit_cast(unsigned short, hb) << 16);
}

// ---------------- prep: esq (numpy pairwise-8 exact), eh fp16, embT fp32, init -----
__global__ void vq_prep(const float* __restrict__ emb, float* __restrict__ esq,
                        uint2* __restrict__ eh2, int* __restrict__ hcnt,
                        double* __restrict__ lsum, float* __restrict__ embT,
                        int use_embT)
{
    const int bid = blockIdx.x;
    const int t = threadIdx.x;
    if (bid == 0 && t == 0) { *hcnt = 0; *lsum = 0.0; }

    if (bid < 4) {
        int k = bid * 256 + t;
        const float* e = emb + (size_t)k * DD;
        float blk[2];
#pragma unroll
        for (int b2 = 0; b2 < 2; ++b2) {
            const float* p = e + b2 * 128;
            float r[8];
#pragma unroll
            for (int j = 0; j < 8; ++j) r[j] = __fmul_rn(p[j], p[j]);
            for (int i = 8; i < 128; i += 8) {
#pragma unroll
                for (int j = 0; j < 8; ++j)
                    r[j] = __fadd_rn(r[j], __fmul_rn(p[i + j], p[i + j]));
            }
            blk[b2] = __fadd_rn(__fadd_rn(__fadd_rn(r[0], r[1]), __fadd_rn(r[2], r[3])),
                                __fadd_rn(__fadd_rn(r[4], r[5]), __fadd_rn(r[6], r[7])));
        }
        esq[k] = __fadd_rn(blk[0], blk[1]);
    } else if (bid < 20) {
        int tid = (bid - 4) * 256 + t;
        const float4* e4 = (const float4*)emb;
#pragma unroll
        for (int i = 0; i < 16; ++i) {
            int idx = i * 4096 + tid;
            float4 v = e4[idx];
            eh2[idx] = make_uint2(pk16(v.x, v.y), pk16(v.z, v.w));
        }
    } else {
        // transpose emb -> embT [d][k] (1 MB, one-time)
        if (!use_embT) return;
        int u = bid - 20;              // 0..15
        int k = u * 64 + (t >> 2);
        int c = t & 3;
        const float4* e4 = (const float4*)(emb + (size_t)k * DD);
#pragma unroll
        for (int i = 0; i < 16; ++i) {
            float4 v = e4[c * 16 + i];
            int d = c * 64 + i * 4;
            embT[(size_t)(d + 0) * KK + k] = v.x;
            embT[(size_t)(d + 1) * KK + k] = v.y;
            embT[(size_t)(d + 2) * KK + k] = v.z;
            embT[(size_t)(d + 3) * KK + k] = v.w;
        }
    }
}

// ---------------- score: A-in-registers MFMA + fused scatter/loss for certain rows --
__launch_bounds__(256, 2)
__global__ void vq_score(const float* __restrict__ z, const float* __restrict__ emb,
                         const _Float16* __restrict__ eh, const float* __restrict__ esq,
                         float* __restrict__ out, int* __restrict__ hlist,
                         int* __restrict__ hcnt, double* __restrict__ lsum,
                         float* __restrict__ hz, int hzcap)
{
    __shared__ __align__(16) float zf[64 * 264];   // 67.6 KB, z fp32 [row][d]
    __shared__ uint2 cand[64][4];
    __shared__ int idxs[64];
    __shared__ float wsum[4];

    const int t = threadIdx.x;
    const int lane = t & 63;
    const int w = t >> 6;
    const int col = lane & 15;
    const int quad = lane >> 4;

    const int n0 = blockIdx.x * 64;
    const int b = n0 >> 12;
    const int hw0 = n0 & (HW - 1);
    const float* zbase = z + (size_t)b * DD * HW;

    // ---- stage z fp32 -> LDS (coalesced global reads, float4 LDS stores)
    {
        const int r = t & 63, dg = t >> 6;
        const float* src = zbase + hw0 + r + (size_t)(dg * 64) * HW;
        float* dst = &zf[r * 264 + dg * 64];
#pragma unroll 4
        for (int i = 0; i < 16; ++i) {
            float4 v;
            v.x = src[(size_t)(4 * i + 0) * HW];
            v.y = src[(size_t)(4 * i + 1) * HW];
            v.z = src[(size_t)(4 * i + 2) * HW];
            v.w = src[(size_t)(4 * i + 3) * HW];
            *(float4*)&dst[i * 4] = v;
        }
    }
    __syncthreads();

    // ---- A-fragments into registers (fp16, RNE), 128 VGPRs
    U16x8 af[4][8];
#pragma unroll
    for (int nt = 0; nt < 4; ++nt)
#pragma unroll
        for (int ds = 0; ds < 8; ++ds) {
            const float* p = &zf[(nt * 16 + col) * 264 + ds * 32 + quad * 8];
            float4 x0 = *(const float4*)p;
            float4 x1 = *(const float4*)(p + 4);
            af[nt][ds].u = make_uint4(pk16(x0.x, x0.y), pk16(x0.z, x0.w),
                                      pk16(x1.x, x1.y), pk16(x1.z, x1.w));
        }

    // ---- main loop: this wave scans codes [w*256, w*256+256)
    unsigned t1[16], t2[16];
#pragma unroll
    for (int i = 0; i < 16; ++i) { t1[i] = 0xFFFFFFFFu; t2[i] = 0xFFFFFFFFu; }

    const uint4* ehq = (const uint4*)eh;
    const int cbase = w * 256;
    for (int ct = 0; ct < 16; ++ct) {
        const int code = cbase + ct * 16 + col;
        const float eq = esq[code];
        const uint4* bp = ehq + (size_t)code * 32 + quad;
        f32x4 acc[4];
#pragma unroll
        for (int nt = 0; nt < 4; ++nt) acc[nt] = (f32x4)0.0f;
#pragma unroll
        for (int ds = 0; ds < 8; ++ds) {
            U16x8 bf;
            bf.u = bp[ds * 4];
#pragma unroll
            for (int nt = 0; nt < 4; ++nt)
                acc[nt] = __builtin_amdgcn_mfma_f32_16x16x32_f16(af[nt][ds].h, bf.h,
                                                                 acc[nt], 0, 0, 0);
        }
#pragma unroll
        for (int nt = 0; nt < 4; ++nt)
#pragma unroll
            for (int r = 0; r < 4; ++r) {
                float s = __fsub_rn(eq, __fmul_rn(2.0f, acc[nt][r]));
                unsigned key = (fkey(s) & 0xFFFFFC00u) | (unsigned)code;
                int mi = nt * 4 + r;
                unsigned mx = max(t1[mi], key);
                t1[mi] = min(t1[mi], key);
                t2[mi] = min(t2[mi], mx);
            }
    }

    // ---- cross-col (16-lane) top2 merge
#pragma unroll
    for (int mi = 0; mi < 16; ++mi) {
        unsigned a = t1[mi], bb = t2[mi];
#pragma unroll
        for (int off = 1; off < 16; off <<= 1) {
            unsigned o1 = __shfl_xor(a, off, 16);
            unsigned o2 = __shfl_xor(bb, off, 16);
            unsigned mx = max(a, o1);
            a = min(a, o1);
            bb = min(min(bb, o2), mx);
        }
        if (col == 0) {
            int row = (mi >> 2) * 16 + quad * 4 + (mi & 3);
            cand[row][w] = make_uint2(a, bb);
        }
    }
    __syncthreads();

    // ---- cross-wave merge + margin routing
    if (t < 64) {
        uint2 c0 = cand[t][0];
        unsigned a = c0.x, bb = c0.y;
#pragma unroll
        for (int ww = 1; ww < 4; ++ww) {
            uint2 c = cand[t][ww];
            unsigned mx = max(a, c.x);
            a = min(a, c.x);
            bb = min(min(bb, c.y), mx);
        }
        float s1 = funkey(a & 0xFFFFFC00u);
        float s2 = funkey(bb & 0xFFFFFC00u);
        int k1 = (int)(a & 1023u);
        if (__fsub_rn(s2, s1) > MARGIN) {
            idxs[t] = k1;
            out[OUT_IDX + n0 + t] = (float)k1;
        } else {
            int pos = atomicAdd(hcnt, 1);
            hlist[pos] = n0 + t;
            idxs[t] = -2 - pos;       // encode pos for the hz copy below
        }
    }
    __syncthreads();

    // ---- fused scatter + loss for certain rows; hz copy for hard rows
    {
        const int rr = t & 63;
        const int dg = t >> 6;
        int idx = idxs[rr];
        float lacc = 0.f;
        if (idx >= 0) {
            const float* erow = emb + (size_t)idx * DD;
            const float* zrow = &zf[rr * 264];
            float* oc = out + (size_t)b * DD * HW + hw0 + rr;
#pragma unroll 4
            for (int dd = 0; dd < 64; ++dd) {
                int d = dg * 64 + dd;
                float e = erow[d];
                float zv = zrow[d];
                oc[(size_t)d * HW] = e;
                float df = e - zv;
                lacc = fmaf(df, df, lacc);
            }
        } else {
            // hard row: stash the exact fp32 z row compactly for vq_hard
            int pos = -2 - idx;
            if (pos < hzcap) {
                float4* dst = (float4*)(hz + (size_t)pos * DD + dg * 64);
                const float4* srcv = (const float4*)(&zf[rr * 264 + dg * 64]);
#pragma unroll
                for (int i = 0; i < 16; ++i) dst[i] = srcv[i];
            }
        }
#pragma unroll
        for (int off = 32; off > 0; off >>= 1) lacc += __shfl_down(lacc, off, 64);
        if (lane == 0) wsum[w] = lacc;
    }
    __syncthreads();
    if (t == 0) {
        double tot = (double)wsum[0] + (double)wsum[1] + (double)wsum[2] + (double)wsum[3];
        atomicAdd(lsum, tot);
    }
}

// ---- hard-path dot products: codes k = 4t+kk, sequential-d fma chain (bit-exact
//      same accumulation order as the previous passing kernel: d = 0..255 ascending)
template<int USET>
static __device__ __forceinline__ void dot_codes(const float4* __restrict__ embT4,
                                                 const float4* __restrict__ emb4,
                                                 const float4* __restrict__ zb4,
                                                 int t, float (&acc_)[8][4])
{
#pragma unroll 2
    for (int dc = 0; dc < 64; ++dc) {
        float4 e0, e1, e2, e3;
        if (USET) {
            // coalesced: lanes read consecutive codes of embT row d
            e0 = embT4[(size_t)(dc * 4 + 0) * 256 + t];
            e1 = embT4[(size_t)(dc * 4 + 1) * 256 + t];
            e2 = embT4[(size_t)(dc * 4 + 2) * 256 + t];
            e3 = embT4[(size_t)(dc * 4 + 3) * 256 + t];
        } else {
            // fallback (tiny ws): gather 4 emb rows + register transpose
            float4 a0 = emb4[(size_t)(4 * t + 0) * 64 + dc];
            float4 a1 = emb4[(size_t)(4 * t + 1) * 64 + dc];
            float4 a2 = emb4[(size_t)(4 * t + 2) * 64 + dc];
            float4 a3 = emb4[(size_t)(4 * t + 3) * 64 + dc];
            e0 = make_float4(a0.x, a1.x, a2.x, a3.x);
            e1 = make_float4(a0.y, a1.y, a2.y, a3.y);
            e2 = make_float4(a0.z, a1.z, a2.z, a3.z);
            e3 = make_float4(a0.w, a1.w, a2.w, a3.w);
        }
#pragma unroll
        for (int j = 0; j < 8; ++j) {
            float4 zv = zb4[j * 64 + dc];          // LDS broadcast, conflict-free
            acc_[j][0] = fmaf(zv.x, e0.x, acc_[j][0]);
            acc_[j][1] = fmaf(zv.x, e0.y, acc_[j][1]);
            acc_[j][2] = fmaf(zv.x, e0.z, acc_[j][2]);
            acc_[j][3] = fmaf(zv.x, e0.w, acc_[j][3]);
            acc_[j][0] = fmaf(zv.y, e1.x, acc_[j][0]);
            acc_[j][1] = fmaf(zv.y, e1.y, acc_[j][1]);
            acc_[j][2] = fmaf(zv.y, e1.z, acc_[j][2]);
            acc_[j][3] = fmaf(zv.y, e1.w, acc_[j][3]);
            acc_[j][0] = fmaf(zv.z, e2.x, acc_[j][0]);
            acc_[j][1] = fmaf(zv.z, e2.y, acc_[j][1]);
            acc_[j][2] = fmaf(zv.z, e2.z, acc_[j][2]);
            acc_[j][3] = fmaf(zv.z, e2.w, acc_[j][3]);
            acc_[j][0] = fmaf(zv.w, e3.x, acc_[j][0]);
            acc_[j][1] = fmaf(zv.w, e3.y, acc_[j][1]);
            acc_[j][2] = fmaf(zv.w, e3.z, acc_[j][2]);
            acc_[j][3] = fmaf(zv.w, e3.w, acc_[j][3]);
        }
    }
}

// ---------------- hard: exact fp32 rescan, barrier-free inner loop -----------------
// z rows come compacted (hz) from vq_score; emb comes pre-transposed (embT) so all
// loads are coalesced and the 1024-code scan is a pure register FMA chain.
__launch_bounds__(256)
__global__ void vq_hard(const float* __restrict__ z, const float* __restrict__ emb,
                        const float* __restrict__ embT, const float* __restrict__ esq,
                        const float* __restrict__ hz, const int* __restrict__ hlist,
                        const int* __restrict__ hcnt, float* __restrict__ out,
                        double* __restrict__ lsum, int hzcap, int use_embT)
{
    __shared__ __align__(16) float zbuf[8 * 256];   // 8 exact fp32 z rows
    __shared__ float chains[8][16];
    __shared__ float zq_s[8];
    __shared__ int rows_s[8];
    __shared__ int idx_s[8];
    __shared__ u64 red[4][8];
    __shared__ float wsum[4];

    const int t = threadIdx.x;
    const int lane = t & 63;
    const int w = t >> 6;
    const int count = *hcnt;
    float lacc = 0.f;

    const float4* embT4 = (const float4*)embT;
    const float4* emb4 = (const float4*)emb;
    const float4* hz4 = (const float4*)hz;
    const float4* zb4 = (const float4*)zbuf;
    const float4 eqv4 = ((const float4*)esq)[t];    // esq[4t .. 4t+3]
    const float eqa[4] = {eqv4.x, eqv4.y, eqv4.z, eqv4.w};

    for (int g = blockIdx.x; g * 8 < count; g += gridDim.x) {
        __syncthreads();
        if (t < 8) {
            int p = g * 8 + t;
            rows_s[t] = (p < count) ? hlist[p] : -1;
        }
        __syncthreads();

        // ---- stage 8 z rows -> LDS (coalesced float4 from hz; strided fallback)
        {
            const int j = t >> 5, dpos = t & 31;    // 32 threads per row, 8 floats each
            const int pos = g * 8 + j;
            const int r = rows_s[j];
            float4 v0 = make_float4(0.f, 0.f, 0.f, 0.f), v1 = v0;
            if (r >= 0) {
                if (pos < hzcap) {
                    v0 = hz4[(size_t)pos * 64 + dpos * 2];
                    v1 = hz4[(size_t)pos * 64 + dpos * 2 + 1];
                } else {
                    const float* zp = z + (size_t)(r >> 12) * (DD * HW) + (r & (HW - 1));
                    const int d0 = dpos * 8;
                    v0.x = zp[(size_t)(d0 + 0) * HW];
                    v0.y = zp[(size_t)(d0 + 1) * HW];
                    v0.z = zp[(size_t)(d0 + 2) * HW];
                    v0.w = zp[(size_t)(d0 + 3) * HW];
                    v1.x = zp[(size_t)(d0 + 4) * HW];
                    v1.y = zp[(size_t)(d0 + 5) * HW];
                    v1.z = zp[(size_t)(d0 + 6) * HW];
                    v1.w = zp[(size_t)(d0 + 7) * HW];
                }
            }
            *(float4*)&zbuf[j * 256 + dpos * 8] = v0;
            *(float4*)&zbuf[j * 256 + dpos * 8 + 4] = v1;
        }
        __syncthreads();

        // ---- zsq: bit-exact numpy pairwise-8 from the staged exact fp32 rows
        if (t < 128) {
            int j = t >> 4, c = t & 15, b2 = c >> 3, jj = c & 7;
            const float* p = &zbuf[j * 256];
            int base = b2 * 128 + jj;
            float v = p[base];
            float acc = __fmul_rn(v, v);
            for (int i = 1; i < 16; ++i) {
                float u = p[base + i * 8];
                acc = __fadd_rn(acc, __fmul_rn(u, u));
            }
            chains[j][c] = acc;
        }
        __syncthreads();
        if (t < 8) {
            const float* c = chains[t];
            float b0 = __fadd_rn(__fadd_rn(__fadd_rn(c[0], c[1]), __fadd_rn(c[2], c[3])),
                                 __fadd_rn(__fadd_rn(c[4], c[5]), __fadd_rn(c[6], c[7])));
            float b1 = __fadd_rn(__fadd_rn(__fadd_rn(c[8], c[9]), __fadd_rn(c[10], c[11])),
                                 __fadd_rn(__fadd_rn(c[12], c[13]), __fadd_rn(c[14], c[15])));
            zq_s[t] = __fadd_rn(b0, b1);
        }
        __syncthreads();

        // ---- fp32 dots: 8 rows x 4 codes per thread, no barriers
        float acc_[8][4];
#pragma unroll
        for (int j = 0; j < 8; ++j)
#pragma unroll
            for (int kk = 0; kk < 4; ++kk) acc_[j][kk] = 0.0f;

        if (use_embT) dot_codes<1>(embT4, emb4, zb4, t, acc_);
        else          dot_codes<0>(embT4, emb4, zb4, t, acc_);

        // ---- per-row argmin (same pack/tie-break as before: min s, then min k)
#pragma unroll
        for (int j = 0; j < 8; ++j) {
            u64 m = ~0ull;
#pragma unroll
            for (int kk = 0; kk < 4; ++kk) {
                float s = __fsub_rn(__fadd_rn(zq_s[j], eqa[kk]),
                                    __fmul_rn(2.0f, acc_[j][kk]));
                u64 p = ((u64)__float_as_uint(s) << 32) | (unsigned)(4 * t + kk);
                m = umin64(m, p);
            }
#pragma unroll
            for (int off = 1; off < 64; off <<= 1)
                m = umin64(m, __shfl_xor(m, off, 64));
            if (lane == 0) red[w][j] = m;
        }
        __syncthreads();
        if (t < 8) {
            u64 m = umin64(umin64(red[0][t], red[1][t]), umin64(red[2][t], red[3][t]));
            int ki = (int)(m & 0xffffffffu);
            idx_s[t] = ki;
            int r = rows_s[t];
            if (r >= 0) out[OUT_IDX + r] = (float)ki;
        }
        __syncthreads();

        // ---- scatter + loss for these 8 rows (z from zbuf, exact)
        for (int p = t; p < 2048; p += 256) {
            int j = p >> 8, d = p & 255;
            int r = rows_s[j];
            if (r >= 0) {
                float e = emb[(size_t)idx_s[j] * DD + d];
                size_t off = (size_t)(r >> 12) * (DD * HW) + (size_t)d * HW + (r & (HW - 1));
                float zv = zbuf[j * 256 + d];
                out[off] = e;
                float df = e - zv;
                lacc = fmaf(df, df, lacc);
            }
        }
    }

#pragma unroll
    for (int off = 32; off > 0; off >>= 1) lacc += __shfl_down(lacc, off, 64);
    if (lane == 0) wsum[w] = lacc;
    __syncthreads();
    if (t == 0) {
        double tot = (double)wsum[0] + (double)wsum[1] + (double)wsum[2] + (double)wsum[3];
        if (tot != 0.0) atomicAdd(lsum, tot);
    }
}

__global__ void vq_final(const double* __restrict__ lsum, float* __restrict__ out)
{
    out[OUT_LOSS] = (float)(0.25 * (lsum[0] / (double)OUT_Z));
}

extern "C" void kernel_launch(void* const* d_in, const int* in_sizes, int n_in,
                              void* d_out, int out_size, void* d_ws, size_t ws_size,
                              hipStream_t stream)
{
    const float* z = (const float*)d_in[0];
    const float* emb = (const float*)d_in[1];
    float* out = (float*)d_out;
    char* w = (char*)d_ws;

    float* esq = (float*)(w + WS_ESQ);
    _Float16* eh = (_Float16*)(w + WS_EH);
    uint2* eh2 = (uint2*)(w + WS_EH);
    int* hlist = (int*)(w + WS_HLIST);
    int* hcnt = (int*)(w + WS_HCNT);
    double* lsum = (double*)(w + WS_LSUM);
    float* embT = (float*)(w + WS_EMBT);
    float* hz = (float*)(w + WS_HZ);

    // runtime guards: degrade gracefully if the workspace is small
    int use_embT = (ws_size >= (size_t)WS_EMBT + (size_t)DD * KK * sizeof(float)) ? 1 : 0;
    int hzcap = 0;
    if (ws_size > (size_t)WS_HZ) {
        size_t c = (ws_size - (size_t)WS_HZ) / ((size_t)DD * sizeof(float));
        hzcap = (c > (size_t)NROWSZ) ? NROWSZ : (int)c;
    }

    vq_prep<<<dim3(36), dim3(256), 0, stream>>>(emb, esq, eh2, hcnt, lsum, embT, use_embT);
    vq_score<<<dim3(1024), dim3(256), 0, stream>>>(z, emb, eh, esq, out, hlist, hcnt, lsum,
                                                   hz, hzcap);
    vq_hard<<<dim3(512), dim3(256), 0, stream>>>(z, emb, embT, esq, hz, hlist, hcnt, out,
                                                 lsum, hzcap, use_embT);
    vq_final<<<dim3(1), dim3(1), 0, stream>>>(lsum, out);
}